// Round 19
// baseline (1298.180 us; speedup 1.0000x reference)
//
#include <hip/hip_runtime.h>
#include <math.h>

namespace {

constexpr int T_STEPS = 512;

typedef _Float16 h8v __attribute__((ext_vector_type(8)));
typedef _Float16 h2v __attribute__((ext_vector_type(2)));
typedef float    f4v __attribute__((ext_vector_type(4)));
typedef int      i4v __attribute__((ext_vector_type(4)));

// rcp-based activations (R13-proven).
__device__ __forceinline__ float sigf(float v) {
  return __builtin_amdgcn_rcpf(1.0f + __builtin_amdgcn_exp2f(-1.442695041f * v));
}
__device__ __forceinline__ float tanh_(float v) {
  return 2.0f * __builtin_amdgcn_rcpf(1.0f + __builtin_amdgcn_exp2f(-2.885390082f * v)) - 1.0f;
}

// Pack weights into MFMA B-fragment load order, fp16 (verified on HW R3-R18).
// PA (layer0): frag f = (w*4+q)*6 + ks: gate = 16*(8q+w)+(l&15),
//   k = 32*ks + 8*(l>>4) + j ; ks 0-1 Wih0, ks 2-5 Whh0.
// PB (layer1): 8 ks: 0-3 Wih1, 4-7 Whh1.
__global__ void pack_w(const float* __restrict__ Wih0, const float* __restrict__ Whh0,
                       const float* __restrict__ Wih1, const float* __restrict__ Whh1,
                       _Float16* __restrict__ PA, _Float16* __restrict__ PB) {
  int idx = blockIdx.x * 256 + threadIdx.x;
  if (idx < 98304) {
    int j = idx & 7, l = (idx >> 3) & 63;
    int f = idx >> 9;
    int ks = f % 6, wq = f / 6;
    int q = wq & 3, w = wq >> 2;
    int gate = 16 * (8 * q + w) + (l & 15);
    int k = 32 * ks + ((l >> 4) << 3) + j;
    float v = (k < 64) ? Wih0[gate * 64 + k] : Whh0[gate * 128 + (k - 64)];
    PA[idx] = (_Float16)v;
  } else if (idx < 98304 + 131072) {
    int i = idx - 98304;
    int j = i & 7, l = (i >> 3) & 63;
    int f = i >> 9;
    int ks = f & 7, wq = f >> 3;
    int q = wq & 3, w = wq >> 2;
    int gate = 16 * (8 * q + w) + (l & 15);
    int k = 32 * ks + ((l >> 4) << 3) + j;
    float v = (k < 128) ? Wih1[gate * 128 + k] : Whh1[gate * 128 + (k - 128)];
    PB[i] = (_Float16)v;
  }
}

// R18 structure (best: 1227us; 128 blocks x 8 rows) + AGPR weight residency.
// R18 post-mortem: per-CU step floor ~= the 320 KB/step L2 weight re-stream
// at ~64 B/cy -- the L2 load port is the wall. Fix (R12's placement, now
// viable because R13 freed the VALU pipe that accvgpr moves would contend
// with): pin W0 (24 frags) + Wih1 q0,1 (8 frags) = 128 AGPRs via "+a"
// (R12-proven no-spill at 2 waves/SIMD); stream only Wih1 q2,3 (64 KB/step,
// LICM-defeated). L2 stream: 320 -> 64 KB/step. Everything else = R18:
// 512 thr (8 waves, 2/SIMD), fused iter j = L0 step j + L1 step j-1, ONE
// barrier/iter, wave w owns units [16w,16w+16) x 4 gates both layers,
// lane-local cell update, c fp32 in regs, Whh1 LDS-resident (128 KB),
// activation-tile rows 8-15 zero-padded (8 valid batch rows/block).
__global__ __attribute__((amdgpu_waves_per_eu(2, 2))) __launch_bounds__(512)
void lstm_block(
    const float* __restrict__ x,
    const _Float16* __restrict__ PA, const _Float16* __restrict__ PB,
    const float* __restrict__ b0, const float* __restrict__ b1,
    const float* __restrict__ Wout, const float* __restrict__ bout,
    float* __restrict__ out) {
  extern __shared__ char smem[];
  h8v* whh = (h8v*)smem;  // Whh1 B-frags: [32 wq][4 ks4][64 l] = 128 KB
  _Float16(*h0t)[4][64][8] = (_Float16(*)[4][64][8])(smem + 131072);          // [2][4][64][8] 8 KB
  _Float16(*h1t)[4][64][8] = (_Float16(*)[4][64][8])(smem + 131072 + 8192);   // 8 KB
  _Float16(*xt)[2][64][8]  = (_Float16(*)[2][64][8])(smem + 131072 + 16384);  // [2][2][64][8] 4 KB

  const int tid = threadIdx.x;
  const int g = blockIdx.x;
  const int w = tid >> 6, l = tid & 63;
  const int lo = l & 15, hi = l >> 4;
  const int unit = 16 * w + lo;
  const int kb_w = w >> 1;
  const int sub_w = (2 * w + (lo >> 3)) & 3;
  const int lanep = sub_w * 16 + hi * 4;  // + r
  const int jw = lo & 7;

  const i4v* PAi = (const i4v*)PA;
  const i4v* PBi = (const i4v*)PB;
  const h8v* PBv = (const h8v*)PB;

  // ---- AGPR-resident weights: 32 frags = 128 AGPRs ("+a", R12-proven) ----
  i4v W0a[4][6];   // layer-0: all 24 frags
  i4v W1a[2][4];   // layer-1 Wih1, q = 0,1 (8 frags)
#pragma unroll
  for (int q = 0; q < 4; ++q)
#pragma unroll
    for (int ks = 0; ks < 6; ++ks) W0a[q][ks] = PAi[((w * 4 + q) * 6 + ks) * 64 + l];
#pragma unroll
  for (int q = 0; q < 2; ++q)
#pragma unroll
    for (int ks = 0; ks < 4; ++ks) W1a[q][ks] = PBi[((w * 4 + q) * 8 + ks) * 64 + l];
#pragma unroll
  for (int q = 0; q < 4; ++q)
#pragma unroll
    for (int ks = 0; ks < 6; ++ks) asm volatile("" : "+a"(W0a[q][ks]));
#pragma unroll
  for (int q = 0; q < 2; ++q)
#pragma unroll
    for (int ks = 0; ks < 4; ++ks) asm volatile("" : "+a"(W1a[q][ks]));

  float bA[4], bB[4];
#pragma unroll
  for (int q = 0; q < 4; ++q) { bA[q] = b0[unit + 128 * q]; bB[q] = b1[unit + 128 * q]; }
  float c0[4] = {0.f, 0.f, 0.f, 0.f}, c1[4] = {0.f, 0.f, 0.f, 0.f};

  // ---- stage Whh1 fragments into LDS ----
  for (int i = tid; i < 8192; i += 512) {
    int l2 = i & 63, f = i >> 6;
    int ks4 = f & 3, wq = f >> 2;
    ((i4v*)whh)[i] = PBi[(wq * 8 + 4 + ks4) * 64 + l2];
  }
  // ---- zero h0t/h1t and BOTH xt buffers (rows 8-15 stay zero forever) ----
  {
    unsigned int* z0 = (unsigned int*)h0t;
    unsigned int* z1 = (unsigned int*)h1t;
    unsigned int* z2 = (unsigned int*)xt;
    for (int i = tid; i < 2048; i += 512) { z0[i] = 0u; z1[i] = 0u; }
    for (int i = tid; i < 1024; i += 512) { z2[i] = 0u; }
  }
  __syncthreads();
  // ---- stage x(0) rows 0-7 ----
  if (tid < 256) {
    int row = tid >> 5, kk = (tid & 31) << 1;
    const float* xp = x + (((long)(g * 8 + row)) * T_STEPS + 0) * 64 + kk;
    float2 v = *(const float2*)xp;
    h2v pxv; pxv.x = (_Float16)v.x; pxv.y = (_Float16)v.y;
    *(h2v*)&xt[0][kk >> 5][(((kk >> 3) & 3) * 16) + row][kk & 7] = pxv;
  }
  __syncthreads();

  // Fused: iter j = A(j) [layer0 step j] + B(j-1) [layer1 step j-1].
  for (int j = 0; j <= T_STEPS; ++j) {
    const int p = j & 1;

    // shared h0(j-1) fragments (A-operand for BOTH layers)
    h8v h00 = *(const h8v*)&h0t[p][0][l][0];
    h8v h01 = *(const h8v*)&h0t[p][1][l][0];
    h8v h02 = *(const h8v*)&h0t[p][2][l][0];
    h8v h03 = *(const h8v*)&h0t[p][3][l][0];

    if (j < T_STEPS) {
      // ---- A(j): layer 0 computes h0(j) ----
      h8v ax0 = *(const h8v*)&xt[p][0][l][0];
      h8v ax1 = *(const h8v*)&xt[p][1][l][0];
      f4v accA[4];
#pragma unroll
      for (int q = 0; q < 4; ++q) {
        f4v z = {bA[q], bA[q], bA[q], bA[q]};
        z = __builtin_amdgcn_mfma_f32_16x16x32_f16(ax0, __builtin_bit_cast(h8v, W0a[q][0]), z, 0, 0, 0);
        z = __builtin_amdgcn_mfma_f32_16x16x32_f16(ax1, __builtin_bit_cast(h8v, W0a[q][1]), z, 0, 0, 0);
        z = __builtin_amdgcn_mfma_f32_16x16x32_f16(h00, __builtin_bit_cast(h8v, W0a[q][2]), z, 0, 0, 0);
        z = __builtin_amdgcn_mfma_f32_16x16x32_f16(h01, __builtin_bit_cast(h8v, W0a[q][3]), z, 0, 0, 0);
        z = __builtin_amdgcn_mfma_f32_16x16x32_f16(h02, __builtin_bit_cast(h8v, W0a[q][4]), z, 0, 0, 0);
        z = __builtin_amdgcn_mfma_f32_16x16x32_f16(h03, __builtin_bit_cast(h8v, W0a[q][5]), z, 0, 0, 0);
        accA[q] = z;
      }
#pragma unroll
      for (int r = 0; r < 4; ++r) {
        float cn = sigf(accA[1][r]) * c0[r] + sigf(accA[0][r]) * tanh_(accA[2][r]);
        c0[r] = cn;
        float hv = sigf(accA[3][r]) * tanh_(cn);
        h0t[p ^ 1][kb_w][lanep + r][jw] = (_Float16)hv;
      }
      if (j + 1 < T_STEPS && tid < 256) {  // stage x(j+1) rows 0-7
        int row = tid >> 5, kk = (tid & 31) << 1;
        const float* xp = x + (((long)(g * 8 + row)) * T_STEPS + (j + 1)) * 64 + kk;
        float2 v = *(const float2*)xp;
        h2v pxv; pxv.x = (_Float16)v.x; pxv.y = (_Float16)v.y;
        *(h2v*)&xt[p ^ 1][kk >> 5][(((kk >> 3) & 3) * 16) + row][kk & 7] = pxv;
      }
    }

    if (j >= 1) {
      // ---- B(j-1): layer 1 computes h1(j-1) ----
      int zoff = 0;
      asm volatile("" : "+v"(zoff));  // keep q2,3 Wih1 loads IN-loop
      h8v f10 = *(const h8v*)&h1t[p][0][l][0];
      h8v f11 = *(const h8v*)&h1t[p][1][l][0];
      h8v f12 = *(const h8v*)&h1t[p][2][l][0];
      h8v f13 = *(const h8v*)&h1t[p][3][l][0];
      h8v gw[2][4];
#pragma unroll
      for (int qq = 0; qq < 2; ++qq)
#pragma unroll
        for (int ks = 0; ks < 4; ++ks)
          gw[qq][ks] = PBv[((w * 4 + 2 + qq) * 8 + ks) * 64 + l + zoff];
      f4v accB[4];
#pragma unroll
      for (int q = 0; q < 4; ++q) {
        const h8v* wb = &whh[((w * 4 + q) * 4) * 64 + l];
        h8v wh0 = wb[0];
        h8v wh1 = wb[64];
        h8v wh2 = wb[128];
        h8v wh3 = wb[192];
        h8v wi0 = (q < 2) ? __builtin_bit_cast(h8v, W1a[q & 1][0]) : gw[q & 1][0];
        h8v wi1 = (q < 2) ? __builtin_bit_cast(h8v, W1a[q & 1][1]) : gw[q & 1][1];
        h8v wi2 = (q < 2) ? __builtin_bit_cast(h8v, W1a[q & 1][2]) : gw[q & 1][2];
        h8v wi3 = (q < 2) ? __builtin_bit_cast(h8v, W1a[q & 1][3]) : gw[q & 1][3];
        f4v z = {bB[q], bB[q], bB[q], bB[q]};
        z = __builtin_amdgcn_mfma_f32_16x16x32_f16(h00, wi0, z, 0, 0, 0);
        z = __builtin_amdgcn_mfma_f32_16x16x32_f16(h01, wi1, z, 0, 0, 0);
        z = __builtin_amdgcn_mfma_f32_16x16x32_f16(h02, wi2, z, 0, 0, 0);
        z = __builtin_amdgcn_mfma_f32_16x16x32_f16(h03, wi3, z, 0, 0, 0);
        z = __builtin_amdgcn_mfma_f32_16x16x32_f16(f10, wh0, z, 0, 0, 0);
        z = __builtin_amdgcn_mfma_f32_16x16x32_f16(f11, wh1, z, 0, 0, 0);
        z = __builtin_amdgcn_mfma_f32_16x16x32_f16(f12, wh2, z, 0, 0, 0);
        z = __builtin_amdgcn_mfma_f32_16x16x32_f16(f13, wh3, z, 0, 0, 0);
        accB[q] = z;
      }
#pragma unroll
      for (int r = 0; r < 4; ++r) {
        float cn = sigf(accB[1][r]) * c1[r] + sigf(accB[0][r]) * tanh_(accB[2][r]);
        c1[r] = cn;
        float hv = sigf(accB[3][r]) * tanh_(cn);
        h1t[p ^ 1][kb_w][lanep + r][jw] = (_Float16)hv;
      }
    }
    __syncthreads();
  }

  // ---- output projection: y = h1(T-1) . Wout^T + bout ; h1(T-1) in h1t[1] ----
  if (tid < 8) {
    float acc = bout[0];
#pragma unroll 4
    for (int u = 0; u < 128; ++u) {
      float hval = (float)h1t[1][u >> 5][(((u >> 3) & 3) * 16) + tid][u & 7];
      acc = fmaf(hval, Wout[u], acc);
    }
    out[g * 8 + tid] = acc;
  }
}

}  // namespace

extern "C" void kernel_launch(void* const* d_in, const int* in_sizes, int n_in,
                              void* d_out, int out_size, void* d_ws, size_t ws_size,
                              hipStream_t stream) {
  const float* x    = (const float*)d_in[0];
  const float* Wih0 = (const float*)d_in[1];
  const float* Whh0 = (const float*)d_in[2];
  const float* b0   = (const float*)d_in[3];
  const float* Wih1 = (const float*)d_in[4];
  const float* Whh1 = (const float*)d_in[5];
  const float* b1   = (const float*)d_in[6];
  const float* Wout = (const float*)d_in[7];
  const float* bout = (const float*)d_in[8];
  float* out = (float*)d_out;

  char* ws = (char*)d_ws;
  _Float16* PA = (_Float16*)ws;             // 196608 B
  _Float16* PB = (_Float16*)(ws + 196608);  // 262144 B

  const int lds_bytes = 131072 + 8192 + 8192 + 4096;  // 151552
  hipFuncSetAttribute((const void*)lstm_block,
                      hipFuncAttributeMaxDynamicSharedMemorySize, lds_bytes);

  pack_w<<<dim3(896), dim3(256), 0, stream>>>(Wih0, Whh0, Wih1, Whh1, PA, PB);
  lstm_block<<<dim3(128), dim3(512), lds_bytes, stream>>>(
      x, PA, PB, b0, b1, Wout, bout, out);
}

// Round 22
// 1222.350 us; speedup vs baseline: 1.0620x; 1.0620x over previous
//
#include <hip/hip_runtime.h>
#include <math.h>

namespace {

constexpr int T_STEPS = 512;

typedef _Float16 h8v __attribute__((ext_vector_type(8)));
typedef _Float16 h2v __attribute__((ext_vector_type(2)));
typedef float    f4v __attribute__((ext_vector_type(4)));

// rcp-based activations (R13-proven: IEEE div was ~half the VALU issue).
__device__ __forceinline__ float sigf(float v) {
  return __builtin_amdgcn_rcpf(1.0f + __builtin_amdgcn_exp2f(-1.442695041f * v));
}
__device__ __forceinline__ float tanh_(float v) {
  return 2.0f * __builtin_amdgcn_rcpf(1.0f + __builtin_amdgcn_exp2f(-2.885390082f * v)) - 1.0f;
}

// Pack weights into MFMA B-fragment load order, fp16 (verified on HW R3-R21).
// PA (layer0): frag f = (w*4+q)*6 + ks: gate = 16*(8q+w)+(l&15),
//   k = 32*ks + 8*(l>>4) + j ; ks 0-1 Wih0, ks 2-5 Whh0.
// PB (layer1): 8 ks: 0-3 Wih1, 4-7 Whh1.
__global__ void pack_w(const float* __restrict__ Wih0, const float* __restrict__ Whh0,
                       const float* __restrict__ Wih1, const float* __restrict__ Whh1,
                       _Float16* __restrict__ PA, _Float16* __restrict__ PB) {
  int idx = blockIdx.x * 256 + threadIdx.x;
  if (idx < 98304) {
    int j = idx & 7, l = (idx >> 3) & 63;
    int f = idx >> 9;
    int ks = f % 6, wq = f / 6;
    int q = wq & 3, w = wq >> 2;
    int gate = 16 * (8 * q + w) + (l & 15);
    int k = 32 * ks + ((l >> 4) << 3) + j;
    float v = (k < 64) ? Wih0[gate * 64 + k] : Whh0[gate * 128 + (k - 64)];
    PA[idx] = (_Float16)v;
  } else if (idx < 98304 + 131072) {
    int i = idx - 98304;
    int j = i & 7, l = (i >> 3) & 63;
    int f = i >> 9;
    int ks = f & 7, wq = f >> 3;
    int q = wq & 3, w = wq >> 2;
    int gate = 16 * (8 * q + w) + (l & 15);
    int k = 32 * ks + ((l >> 4) << 3) + j;
    float v = (k < 128) ? Wih1[gate * 128 + k] : Whh1[gate * 128 + (k - 128)];
    PB[i] = (_Float16)v;
  }
}

// FINAL (champion R18, 1227us): 128 blocks x 8 batch rows, 512 threads
// (8 waves, 2/SIMD), 1 block/CU (LDS 151 KB). Fused pipeline: iter j =
// layer0 step j + layer1 step j-1 (independent), ONE barrier/iter; wave w
// owns units [16w,16w+16) x 4 gate types for both layers; lane-local cell
// update, c fp32 in registers; rcp/exp2 activations. Weights: Whh1
// LDS-resident (128 KB); W0/Wih1 compiler-rematerialized from L2
// (~320 KB/step -- R19 proved this stream is prefetched off the critical
// path). Activation-tile rows 8-15 zero-padded (8 valid rows/block; padding
// rows compute finite garbage that never escapes).
// Session ledger: AGPR residency rejected (builtins insert v_accvgpr_read
// moves, R12/R19; inline-asm MFMA corrupts via unmanaged hazards, R20/R21);
// 1024-thread blocks rejected (allocator pins 64 VGPR -> spill, R8/R14/R15);
// cross-block pipelines rejected (XCD coherence -> HBM round-trips, R3).
__global__ __attribute__((amdgpu_waves_per_eu(2, 2))) __launch_bounds__(512)
void lstm_block(
    const float* __restrict__ x,
    const _Float16* __restrict__ PA, const _Float16* __restrict__ PB,
    const float* __restrict__ b0, const float* __restrict__ b1,
    const float* __restrict__ Wout, const float* __restrict__ bout,
    float* __restrict__ out) {
  extern __shared__ char smem[];
  h8v* whh = (h8v*)smem;  // Whh1 B-frags: [32 wq][4 ks4][64 l] = 128 KB
  _Float16(*h0t)[4][64][8] = (_Float16(*)[4][64][8])(smem + 131072);          // [2][4][64][8] 8 KB
  _Float16(*h1t)[4][64][8] = (_Float16(*)[4][64][8])(smem + 131072 + 8192);   // 8 KB
  _Float16(*xt)[2][64][8]  = (_Float16(*)[2][64][8])(smem + 131072 + 16384);  // [2][2][64][8] 4 KB

  const int tid = threadIdx.x;
  const int g = blockIdx.x;
  const int w = tid >> 6, l = tid & 63;
  const int lo = l & 15, hi = l >> 4;
  const int unit = 16 * w + lo;
  const int kb_w = w >> 1;
  const int sub_w = (2 * w + (lo >> 3)) & 3;
  const int lanep = sub_w * 16 + hi * 4;  // + r
  const int jw = lo & 7;

  // ---- persistent register weights (compiler may remat -- measured OK) ----
  const h8v* PAv = (const h8v*)PA;
  const h8v* PBv = (const h8v*)PB;
  h8v W0[4][6], W1[4][4];
#pragma unroll
  for (int q = 0; q < 4; ++q) {
#pragma unroll
    for (int ks = 0; ks < 6; ++ks) W0[q][ks] = PAv[((w * 4 + q) * 6 + ks) * 64 + l];
#pragma unroll
    for (int ks = 0; ks < 4; ++ks) W1[q][ks] = PBv[((w * 4 + q) * 8 + ks) * 64 + l];
  }
#pragma unroll
  for (int q = 0; q < 4; ++q) {
#pragma unroll
    for (int ks = 0; ks < 6; ++ks) asm volatile("" : "+v"(W0[q][ks]));
#pragma unroll
    for (int ks = 0; ks < 4; ++ks) asm volatile("" : "+v"(W1[q][ks]));
  }
  float bA[4], bB[4];
#pragma unroll
  for (int q = 0; q < 4; ++q) { bA[q] = b0[unit + 128 * q]; bB[q] = b1[unit + 128 * q]; }
  float c0[4] = {0.f, 0.f, 0.f, 0.f}, c1[4] = {0.f, 0.f, 0.f, 0.f};

  // ---- stage Whh1 fragments into LDS ----
  for (int i = tid; i < 8192; i += 512) {
    int l2 = i & 63, f = i >> 6;
    int ks4 = f & 3, wq = f >> 2;
    whh[i] = PBv[(wq * 8 + 4 + ks4) * 64 + l2];
  }
  // ---- zero h0t/h1t and BOTH xt buffers (rows 8-15 stay zero forever) ----
  {
    unsigned int* z0 = (unsigned int*)h0t;
    unsigned int* z1 = (unsigned int*)h1t;
    unsigned int* z2 = (unsigned int*)xt;
    for (int i = tid; i < 2048; i += 512) { z0[i] = 0u; z1[i] = 0u; }
    for (int i = tid; i < 1024; i += 512) { z2[i] = 0u; }
  }
  __syncthreads();
  // ---- stage x(0) rows 0-7 ----
  if (tid < 256) {
    int row = tid >> 5, kk = (tid & 31) << 1;
    const float* xp = x + (((long)(g * 8 + row)) * T_STEPS + 0) * 64 + kk;
    float2 v = *(const float2*)xp;
    h2v pxv; pxv.x = (_Float16)v.x; pxv.y = (_Float16)v.y;
    *(h2v*)&xt[0][kk >> 5][(((kk >> 3) & 3) * 16) + row][kk & 7] = pxv;
  }
  __syncthreads();

  // Fused: iter j = A(j) [layer0 step j] + B(j-1) [layer1 step j-1].
  for (int j = 0; j <= T_STEPS; ++j) {
    const int p = j & 1;

    // shared h0(j-1) fragments (A-operand for BOTH layers)
    h8v h00 = *(const h8v*)&h0t[p][0][l][0];
    h8v h01 = *(const h8v*)&h0t[p][1][l][0];
    h8v h02 = *(const h8v*)&h0t[p][2][l][0];
    h8v h03 = *(const h8v*)&h0t[p][3][l][0];

    if (j < T_STEPS) {
      // ---- A(j): layer 0 computes h0(j) ----
      h8v ax0 = *(const h8v*)&xt[p][0][l][0];
      h8v ax1 = *(const h8v*)&xt[p][1][l][0];
      f4v accA[4];
#pragma unroll
      for (int q = 0; q < 4; ++q) {
        f4v z = {bA[q], bA[q], bA[q], bA[q]};
        z = __builtin_amdgcn_mfma_f32_16x16x32_f16(ax0, W0[q][0], z, 0, 0, 0);
        z = __builtin_amdgcn_mfma_f32_16x16x32_f16(ax1, W0[q][1], z, 0, 0, 0);
        z = __builtin_amdgcn_mfma_f32_16x16x32_f16(h00, W0[q][2], z, 0, 0, 0);
        z = __builtin_amdgcn_mfma_f32_16x16x32_f16(h01, W0[q][3], z, 0, 0, 0);
        z = __builtin_amdgcn_mfma_f32_16x16x32_f16(h02, W0[q][4], z, 0, 0, 0);
        z = __builtin_amdgcn_mfma_f32_16x16x32_f16(h03, W0[q][5], z, 0, 0, 0);
        accA[q] = z;
      }
#pragma unroll
      for (int r = 0; r < 4; ++r) {
        float cn = sigf(accA[1][r]) * c0[r] + sigf(accA[0][r]) * tanh_(accA[2][r]);
        c0[r] = cn;
        float hv = sigf(accA[3][r]) * tanh_(cn);
        h0t[p ^ 1][kb_w][lanep + r][jw] = (_Float16)hv;
      }
      if (j + 1 < T_STEPS && tid < 256) {  // stage x(j+1) rows 0-7
        int row = tid >> 5, kk = (tid & 31) << 1;
        const float* xp = x + (((long)(g * 8 + row)) * T_STEPS + (j + 1)) * 64 + kk;
        float2 v = *(const float2*)xp;
        h2v pxv; pxv.x = (_Float16)v.x; pxv.y = (_Float16)v.y;
        *(h2v*)&xt[p ^ 1][kk >> 5][(((kk >> 3) & 3) * 16) + row][kk & 7] = pxv;
      }
    }

    if (j >= 1) {
      // ---- B(j-1): layer 1 computes h1(j-1) ----
      h8v f10 = *(const h8v*)&h1t[p][0][l][0];
      h8v f11 = *(const h8v*)&h1t[p][1][l][0];
      h8v f12 = *(const h8v*)&h1t[p][2][l][0];
      h8v f13 = *(const h8v*)&h1t[p][3][l][0];
      f4v accB[4];
#pragma unroll
      for (int q = 0; q < 4; ++q) {
        const h8v* wb = &whh[((w * 4 + q) * 4) * 64 + l];
        h8v wh0 = wb[0];
        h8v wh1 = wb[64];
        h8v wh2 = wb[128];
        h8v wh3 = wb[192];
        f4v z = {bB[q], bB[q], bB[q], bB[q]};
        z = __builtin_amdgcn_mfma_f32_16x16x32_f16(h00, W1[q][0], z, 0, 0, 0);
        z = __builtin_amdgcn_mfma_f32_16x16x32_f16(h01, W1[q][1], z, 0, 0, 0);
        z = __builtin_amdgcn_mfma_f32_16x16x32_f16(h02, W1[q][2], z, 0, 0, 0);
        z = __builtin_amdgcn_mfma_f32_16x16x32_f16(h03, W1[q][3], z, 0, 0, 0);
        z = __builtin_amdgcn_mfma_f32_16x16x32_f16(f10, wh0, z, 0, 0, 0);
        z = __builtin_amdgcn_mfma_f32_16x16x32_f16(f11, wh1, z, 0, 0, 0);
        z = __builtin_amdgcn_mfma_f32_16x16x32_f16(f12, wh2, z, 0, 0, 0);
        z = __builtin_amdgcn_mfma_f32_16x16x32_f16(f13, wh3, z, 0, 0, 0);
        accB[q] = z;
      }
#pragma unroll
      for (int r = 0; r < 4; ++r) {
        float cn = sigf(accB[1][r]) * c1[r] + sigf(accB[0][r]) * tanh_(accB[2][r]);
        c1[r] = cn;
        float hv = sigf(accB[3][r]) * tanh_(cn);
        h1t[p ^ 1][kb_w][lanep + r][jw] = (_Float16)hv;
      }
    }
    __syncthreads();
  }

  // ---- output projection: y = h1(T-1) . Wout^T + bout ; h1(T-1) in h1t[1] ----
  if (tid < 8) {
    float acc = bout[0];
#pragma unroll 4
    for (int u = 0; u < 128; ++u) {
      float hval = (float)h1t[1][u >> 5][(((u >> 3) & 3) * 16) + tid][u & 7];
      acc = fmaf(hval, Wout[u], acc);
    }
    out[g * 8 + tid] = acc;
  }
}

}  // namespace

extern "C" void kernel_launch(void* const* d_in, const int* in_sizes, int n_in,
                              void* d_out, int out_size, void* d_ws, size_t ws_size,
                              hipStream_t stream) {
  const float* x    = (const float*)d_in[0];
  const float* Wih0 = (const float*)d_in[1];
  const float* Whh0 = (const float*)d_in[2];
  const float* b0   = (const float*)d_in[3];
  const float* Wih1 = (const float*)d_in[4];
  const float* Whh1 = (const float*)d_in[5];
  const float* b1   = (const float*)d_in[6];
  const float* Wout = (const float*)d_in[7];
  const float* bout = (const float*)d_in[8];
  float* out = (float*)d_out;

  char* ws = (char*)d_ws;
  _Float16* PA = (_Float16*)ws;             // 196608 B
  _Float16* PB = (_Float16*)(ws + 196608);  // 262144 B

  const int lds_bytes = 131072 + 8192 + 8192 + 4096;  // 151552
  hipFuncSetAttribute((const void*)lstm_block,
                      hipFuncAttributeMaxDynamicSharedMemorySize, lds_bytes);

  pack_w<<<dim3(896), dim3(256), 0, stream>>>(Wih0, Whh0, Wih1, Whh1, PA, PB);
  lstm_block<<<dim3(128), dim3(512), lds_bytes, stream>>>(
      x, PA, PB, b0, b1, Wout, bout, out);
}